// Round 3
// baseline (524.057 us; speedup 1.0000x reference)
//
#include <hip/hip_runtime.h>
#include <math.h>

constexpr int B = 32, S = 4096, H = 512;
constexpr int BDIM = 256;          // 4 waves of 64
constexpr int MAX_SPLIT = 64;      // blocks per batch row-range split
constexpr float LOG2E = 1.44269504088896340736f;
constexpr float DEFER_THR = 11.5415603f;   // 8 nats in log2 domain

typedef float f4 __attribute__((ext_vector_type(4)));

// ---------------------------------------------------------------------------
// Kernel 1: u[b,k] = (sum_h h_t[b,h] * W[h,k]) * log2(e)   (tiny: 32x512)
// Also zeroes the per-batch completion counters for this call.
// ---------------------------------------------------------------------------
__global__ __launch_bounds__(BDIM) void u_kernel(const float* __restrict__ h_t,
                                                 const float* __restrict__ W,
                                                 float* __restrict__ u,
                                                 int* __restrict__ cnt) {
    const int b = blockIdx.y;
    const int k = blockIdx.x * BDIM + threadIdx.x;
    if (blockIdx.x == 0 && b == 0 && threadIdx.x < B) cnt[threadIdx.x] = 0;
    __shared__ float hs[H];
    for (int i = threadIdx.x; i < H; i += BDIM) hs[i] = h_t[b * H + i];
    __syncthreads();
    float a0 = 0.f, a1 = 0.f, a2 = 0.f, a3 = 0.f;
#pragma unroll 8
    for (int h = 0; h < H; h += 4) {
        a0 = fmaf(hs[h],     W[(size_t)(h)     * H + k], a0);
        a1 = fmaf(hs[h + 1], W[(size_t)(h + 1) * H + k], a1);
        a2 = fmaf(hs[h + 2], W[(size_t)(h + 2) * H + k], a2);
        a3 = fmaf(hs[h + 3], W[(size_t)(h + 3) * H + k], a3);
    }
    u[b * H + k] = ((a0 + a1) + (a2 + a3)) * LOG2E;
}

// ---------------------------------------------------------------------------
// Kernel 2: fused single pass over context (defer-max online softmax, log2
// domain) + block partial reduce in LDS + last-block-per-batch finalize.
// ---------------------------------------------------------------------------
__global__ __launch_bounds__(BDIM) void flash_kernel(const float* __restrict__ ctx,
                                                     const float* __restrict__ h_t,
                                                     const float* __restrict__ u,
                                                     const int* __restrict__ posp,
                                                     float* __restrict__ newbuf,
                                                     float* __restrict__ pacc,
                                                     float* __restrict__ pml,
                                                     int* __restrict__ cnt,
                                                     float* __restrict__ cntx,
                                                     int nsplit) {
    const int b     = blockIdx.y;
    const int split = blockIdx.x;
    const int w     = threadIdx.x >> 6;
    const int lane  = threadIdx.x & 63;
    const int rpb   = S / nsplit;            // rows per block
    const int s0    = split * rpb;
    int pos = posp[0] % S; if (pos < 0) pos += S;

    const f4* ub = (const f4*)(u + (size_t)b * H);
    const f4 u0 = ub[lane], u1 = ub[64 + lane];
    const f4* hb = (const f4*)(h_t + (size_t)b * H);
    const f4 h0 = hb[lane], h1 = hb[64 + lane];

    float m = -INFINITY, l = 0.f;
    f4 a0 = {0.f, 0.f, 0.f, 0.f}, a1 = {0.f, 0.f, 0.f, 0.f};

#pragma unroll 4
    for (int s = s0 + w; s < s0 + rpb; s += 4) {
        const f4* crow = (const f4*)(ctx + ((size_t)b * S + s) * H);
        const f4 c0 = __builtin_nontemporal_load(crow + lane);
        const f4 c1 = __builtin_nontemporal_load(crow + 64 + lane);

        f4* orow = (f4*)(newbuf + ((size_t)b * S + s) * H);
        const f4 o0 = (s == pos) ? h0 : c0;
        const f4 o1 = (s == pos) ? h1 : c1;
        __builtin_nontemporal_store(o0, orow + lane);
        __builtin_nontemporal_store(o1, orow + 64 + lane);

        // dot in log2 domain (u pre-scaled by log2e)
        float d = c0.x * u0.x + c0.y * u0.y + c0.z * u0.z + c0.w * u0.w
                + c1.x * u1.x + c1.y * u1.y + c1.z * u1.z + c1.w * u1.w;
#pragma unroll
        for (int off = 32; off >= 1; off >>= 1) d += __shfl_xor(d, off);

        if (d > m + DEFER_THR) {   // wave-uniform, rare: rescale to new max
            const float sc = exp2f(m - d);   // first time: exp2(-inf)=0
            a0 *= sc; a1 *= sc; l *= sc; m = d;
        }
        const float p = exp2f(d - m);        // bounded by e^8
        a0 += p * c0;
        a1 += p * c1;
        l  += p;
    }

    // ---- block-level reduce of 4 wave partials via LDS ----
    __shared__ float lacc[4][H];
    __shared__ float lml[4][2];
    f4* dst = (f4*)&lacc[w][0];
    dst[lane] = a0; dst[64 + lane] = a1;
    if (lane == 0) { lml[w][0] = m; lml[w][1] = l; }
    __syncthreads();

    const float m0 = lml[0][0], m1 = lml[1][0], m2 = lml[2][0], m3 = lml[3][0];
    const float M  = fmaxf(fmaxf(m0, m1), fmaxf(m2, m3));
    const float e0 = exp2f(m0 - M), e1 = exp2f(m1 - M);
    const float e2 = exp2f(m2 - M), e3 = exp2f(m3 - M);

    const int t    = threadIdx.x;
    const int pidx = b * nsplit + split;
    const float ca = e0 * lacc[0][t]       + e1 * lacc[1][t]
                   + e2 * lacc[2][t]       + e3 * lacc[3][t];
    const float cb = e0 * lacc[0][256 + t] + e1 * lacc[1][256 + t]
                   + e2 * lacc[2][256 + t] + e3 * lacc[3][256 + t];
    pacc[(size_t)pidx * H + t]       = ca;
    pacc[(size_t)pidx * H + 256 + t] = cb;
    if (t == 0) {
        const float L = e0 * lml[0][1] + e1 * lml[1][1]
                      + e2 * lml[2][1] + e3 * lml[3][1];
        pml[2 * pidx] = M; pml[2 * pidx + 1] = L;
    }

    // ---- last block for this batch finalizes cntx[b,:] ----
    __threadfence();                 // release: all threads' partial stores
    __syncthreads();                 // all fences done before the atomic
    __shared__ int lastf;
    if (t == 0) lastf = (atomicAdd(&cnt[b], 1) == nsplit - 1);
    __syncthreads();
    if (!lastf) return;
    __threadfence();                 // acquire: invalidate stale cached lines

    __shared__ float fm[MAX_SPLIT], fl[MAX_SPLIT];
    if (t < nsplit) {
        fm[t] = pml[2 * (b * nsplit + t)];
        fl[t] = pml[2 * (b * nsplit + t) + 1];
    }
    __syncthreads();
    float Mg = -INFINITY;
    for (int p = 0; p < nsplit; ++p) Mg = fmaxf(Mg, fm[p]);
    float L = 0.f, x0 = 0.f, x1 = 0.f;
#pragma unroll 4
    for (int p = 0; p < nsplit; ++p) {
        const float e = exp2f(fm[p] - Mg);
        L  = fmaf(e, fl[p], L);
        x0 = fmaf(e, pacc[(size_t)(b * nsplit + p) * H + t],       x0);
        x1 = fmaf(e, pacc[(size_t)(b * nsplit + p) * H + 256 + t], x1);
    }
    cntx[b * H + t]       = x0 / L;
    cntx[b * H + 256 + t] = x1 / L;
}

// ---------------------------------------------------------------------------
extern "C" void kernel_launch(void* const* d_in, const int* in_sizes, int n_in,
                              void* d_out, int out_size, void* d_ws, size_t ws_size,
                              hipStream_t stream) {
    const float* h_t = (const float*)d_in[0];
    const float* ctx = (const float*)d_in[1];
    const float* W   = (const float*)d_in[2];
    const int*   pos = (const int*)d_in[3];

    float* out    = (float*)d_out;
    float* cntx   = out;                     // [B,H]
    float* newbuf = out + (size_t)B * H;     // [B,S,H]

    // workspace layout: u [B*H] | pacc [B*nsplit*H] | pml [B*nsplit*2] | cnt [B]
    char*  ws = (char*)d_ws;
    float* u  = (float*)ws;
    const size_t u_bytes = (size_t)B * H * sizeof(float);

    int nsplit = MAX_SPLIT;
    while (nsplit > 1) {
        const size_t need = u_bytes
                          + (size_t)B * nsplit * H * sizeof(float)
                          + (size_t)B * nsplit * 2 * sizeof(float)
                          + (size_t)B * sizeof(int);
        if (need <= ws_size) break;
        nsplit >>= 1;
    }
    float* pacc = (float*)(ws + u_bytes);
    float* pml  = pacc + (size_t)B * nsplit * H;
    int*   cnt  = (int*)(pml + (size_t)B * nsplit * 2);

    u_kernel<<<dim3(H / BDIM, B), BDIM, 0, stream>>>(h_t, W, u, cnt);
    flash_kernel<<<dim3(nsplit, B), BDIM, 0, stream>>>(ctx, h_t, u, pos, newbuf,
                                                       pacc, pml, cnt, cntx, nsplit);
}

// Round 4
// 122.578 us; speedup vs baseline: 4.2753x; 4.2753x over previous
//
#include <hip/hip_runtime.h>
#include <math.h>

constexpr int B = 32, S = 4096, H = 512;
constexpr int BDIM = 256;          // 4 waves of 64
constexpr int MAX_SPLIT = 64;      // blocks per batch row-range split
constexpr float LOG2E = 1.44269504088896340736f;
constexpr float DEFER_THR = 11.5415603f;   // 8 nats in log2 domain

typedef float f4 __attribute__((ext_vector_type(4)));

// ---------------------------------------------------------------------------
// Kernel 1: u[b,k] = (sum_h h_t[b,h] * W[h,k]) * log2(e)   (tiny: 32x512)
// ---------------------------------------------------------------------------
__global__ __launch_bounds__(BDIM) void u_kernel(const float* __restrict__ h_t,
                                                 const float* __restrict__ W,
                                                 float* __restrict__ u) {
    const int b = blockIdx.y;
    const int k = blockIdx.x * BDIM + threadIdx.x;
    __shared__ float hs[H];
    for (int i = threadIdx.x; i < H; i += BDIM) hs[i] = h_t[b * H + i];
    __syncthreads();
    float a0 = 0.f, a1 = 0.f, a2 = 0.f, a3 = 0.f;
#pragma unroll 8
    for (int h = 0; h < H; h += 4) {
        a0 = fmaf(hs[h],     W[(size_t)(h)     * H + k], a0);
        a1 = fmaf(hs[h + 1], W[(size_t)(h + 1) * H + k], a1);
        a2 = fmaf(hs[h + 2], W[(size_t)(h + 2) * H + k], a2);
        a3 = fmaf(hs[h + 3], W[(size_t)(h + 3) * H + k], a3);
    }
    u[b * H + k] = ((a0 + a1) + (a2 + a3)) * LOG2E;
}

// ---------------------------------------------------------------------------
// Kernel 2: fused single pass over context (defer-max online softmax, log2
// domain) + block-level partial reduce in LDS -> one partial per block.
// ctx loads are PLAIN (we want L3 to retain ctx across graph replays);
// newbuf stores are nontemporal (don't displace ctx in L3).
// ---------------------------------------------------------------------------
__global__ __launch_bounds__(BDIM) void flash_kernel(const float* __restrict__ ctx,
                                                     const float* __restrict__ h_t,
                                                     const float* __restrict__ u,
                                                     const int* __restrict__ posp,
                                                     float* __restrict__ newbuf,
                                                     float* __restrict__ pacc,
                                                     float* __restrict__ pml,
                                                     int nsplit) {
    const int b     = blockIdx.y;
    const int split = blockIdx.x;
    const int w     = threadIdx.x >> 6;
    const int lane  = threadIdx.x & 63;
    const int rpb   = S / nsplit;            // rows per block
    const int s0    = split * rpb;
    int pos = posp[0] % S; if (pos < 0) pos += S;

    const f4* ub = (const f4*)(u + (size_t)b * H);
    const f4 u0 = ub[lane], u1 = ub[64 + lane];
    const f4* hb = (const f4*)(h_t + (size_t)b * H);
    const f4 h0 = hb[lane], h1 = hb[64 + lane];

    float m = -INFINITY, l = 0.f;
    f4 a0 = {0.f, 0.f, 0.f, 0.f}, a1 = {0.f, 0.f, 0.f, 0.f};

#pragma unroll 4
    for (int s = s0 + w; s < s0 + rpb; s += 4) {
        const f4* crow = (const f4*)(ctx + ((size_t)b * S + s) * H);
        const f4 c0 = crow[lane];
        const f4 c1 = crow[64 + lane];

        f4* orow = (f4*)(newbuf + ((size_t)b * S + s) * H);
        const f4 o0 = (s == pos) ? h0 : c0;
        const f4 o1 = (s == pos) ? h1 : c1;
        __builtin_nontemporal_store(o0, orow + lane);
        __builtin_nontemporal_store(o1, orow + 64 + lane);

        // dot in log2 domain (u pre-scaled by log2e)
        float d = c0.x * u0.x + c0.y * u0.y + c0.z * u0.z + c0.w * u0.w
                + c1.x * u1.x + c1.y * u1.y + c1.z * u1.z + c1.w * u1.w;
#pragma unroll
        for (int off = 32; off >= 1; off >>= 1) d += __shfl_xor(d, off);

        if (d > m + DEFER_THR) {   // wave-uniform, rare: rescale to new max
            const float sc = exp2f(m - d);   // first time: exp2(-inf)=0
            a0 *= sc; a1 *= sc; l *= sc; m = d;
        }
        const float p = exp2f(d - m);        // bounded by e^8
        a0 += p * c0;
        a1 += p * c1;
        l  += p;
    }

    // ---- block-level reduce of 4 wave partials via LDS ----
    __shared__ float lacc[4][H];
    __shared__ float lml[4][2];
    f4* dst = (f4*)&lacc[w][0];
    dst[lane] = a0; dst[64 + lane] = a1;
    if (lane == 0) { lml[w][0] = m; lml[w][1] = l; }
    __syncthreads();

    const float m0 = lml[0][0], m1 = lml[1][0], m2 = lml[2][0], m3 = lml[3][0];
    const float M  = fmaxf(fmaxf(m0, m1), fmaxf(m2, m3));
    const float e0 = exp2f(m0 - M), e1 = exp2f(m1 - M);
    const float e2 = exp2f(m2 - M), e3 = exp2f(m3 - M);

    const int t    = threadIdx.x;
    const int pidx = b * nsplit + split;
    const float ca = e0 * lacc[0][t]       + e1 * lacc[1][t]
                   + e2 * lacc[2][t]       + e3 * lacc[3][t];
    const float cb = e0 * lacc[0][256 + t] + e1 * lacc[1][256 + t]
                   + e2 * lacc[2][256 + t] + e3 * lacc[3][256 + t];
    pacc[(size_t)pidx * H + t]       = ca;
    pacc[(size_t)pidx * H + 256 + t] = cb;
    if (t == 0) {
        const float L = e0 * lml[0][1] + e1 * lml[1][1]
                      + e2 * lml[2][1] + e3 * lml[3][1];
        pml[2 * pidx] = M; pml[2 * pidx + 1] = L;
    }
}

// ---------------------------------------------------------------------------
// Kernel 3: combine per-block partials -> cntx[b,:].  grid = (B, 2);
// block handles 256 columns (one per thread).
// ---------------------------------------------------------------------------
__global__ __launch_bounds__(BDIM) void combine_kernel(const float* __restrict__ pacc,
                                                       const float* __restrict__ pml,
                                                       float* __restrict__ cntx,
                                                       int nsplit) {
    const int b    = blockIdx.x;
    const int half = blockIdx.y;
    const int t    = threadIdx.x;
    const int col  = half * 256 + t;

    __shared__ float lm[MAX_SPLIT], ll[MAX_SPLIT];
    for (int p = t; p < nsplit; p += BDIM) {
        lm[p] = pml[2 * (b * nsplit + p)];
        ll[p] = pml[2 * (b * nsplit + p) + 1];
    }
    __syncthreads();

    float M = -INFINITY;
    for (int p = 0; p < nsplit; ++p) M = fmaxf(M, lm[p]);

    float acc = 0.f, L = 0.f;
#pragma unroll 4
    for (int p = 0; p < nsplit; ++p) {
        const float e = exp2f(lm[p] - M);
        L   = fmaf(e, ll[p], L);
        acc = fmaf(e, pacc[(size_t)(b * nsplit + p) * H + col], acc);
    }
    cntx[b * H + col] = acc / L;
}

// ---------------------------------------------------------------------------
extern "C" void kernel_launch(void* const* d_in, const int* in_sizes, int n_in,
                              void* d_out, int out_size, void* d_ws, size_t ws_size,
                              hipStream_t stream) {
    const float* h_t = (const float*)d_in[0];
    const float* ctx = (const float*)d_in[1];
    const float* W   = (const float*)d_in[2];
    const int*   pos = (const int*)d_in[3];

    float* out    = (float*)d_out;
    float* cntx   = out;                     // [B,H]
    float* newbuf = out + (size_t)B * H;     // [B,S,H]

    // workspace layout: u [B*H] | pacc [B*nsplit*H] | pml [B*nsplit*2]
    char*  ws = (char*)d_ws;
    float* u  = (float*)ws;
    const size_t u_bytes = (size_t)B * H * sizeof(float);

    int nsplit = MAX_SPLIT;
    while (nsplit > 1) {
        const size_t need = u_bytes
                          + (size_t)B * nsplit * H * sizeof(float)
                          + (size_t)B * nsplit * 2 * sizeof(float);
        if (need <= ws_size) break;
        nsplit >>= 1;
    }
    float* pacc = (float*)(ws + u_bytes);
    float* pml  = pacc + (size_t)B * nsplit * H;

    u_kernel<<<dim3(H / BDIM, B), BDIM, 0, stream>>>(h_t, W, u);
    flash_kernel<<<dim3(nsplit, B), BDIM, 0, stream>>>(ctx, h_t, u, pos, newbuf,
                                                       pacc, pml, nsplit);
    combine_kernel<<<dim3(B, 2), BDIM, 0, stream>>>(pacc, pml, cntx, nsplit);
}

// Round 5
// 117.743 us; speedup vs baseline: 4.4509x; 1.0411x over previous
//
#include <hip/hip_runtime.h>
#include <math.h>

constexpr int B = 32, S = 4096, H = 512;
constexpr int BDIM = 256;          // 4 waves of 64
constexpr int MAX_SPLIT = 64;      // blocks per batch row-range split
constexpr float LOG2E = 1.44269504088896340736f;
constexpr float DEFER_THR = 11.5415603f;   // 8 nats in log2 domain

typedef float f4 __attribute__((ext_vector_type(4)));

__device__ __forceinline__ float dot8(const f4 c0, const f4 c1,
                                      const f4 u0, const f4 u1) {
    float d = c0.x * u0.x;
    d = fmaf(c0.y, u0.y, d); d = fmaf(c0.z, u0.z, d); d = fmaf(c0.w, u0.w, d);
    d = fmaf(c1.x, u1.x, d); d = fmaf(c1.y, u1.y, d);
    d = fmaf(c1.z, u1.z, d); d = fmaf(c1.w, u1.w, d);
    return d;
}

// ---------------------------------------------------------------------------
// Kernel 1: u[b,k] = (sum_h h_t[b,h] * W[h,k]) * log2(e)   (tiny: 32x512)
// ---------------------------------------------------------------------------
__global__ __launch_bounds__(BDIM) void u_kernel(const float* __restrict__ h_t,
                                                 const float* __restrict__ W,
                                                 float* __restrict__ u) {
    const int b = blockIdx.y;
    const int k = blockIdx.x * BDIM + threadIdx.x;
    __shared__ float hs[H];
    for (int i = threadIdx.x; i < H; i += BDIM) hs[i] = h_t[b * H + i];
    __syncthreads();
    float a0 = 0.f, a1 = 0.f, a2 = 0.f, a3 = 0.f;
#pragma unroll 8
    for (int h = 0; h < H; h += 4) {
        a0 = fmaf(hs[h],     W[(size_t)(h)     * H + k], a0);
        a1 = fmaf(hs[h + 1], W[(size_t)(h + 1) * H + k], a1);
        a2 = fmaf(hs[h + 2], W[(size_t)(h + 2) * H + k], a2);
        a3 = fmaf(hs[h + 3], W[(size_t)(h + 3) * H + k], a3);
    }
    u[b * H + k] = ((a0 + a1) + (a2 + a3)) * LOG2E;
}

// ---------------------------------------------------------------------------
// Kernel 2: pure streaming pass. Two independent softmax streams per wave
// (parallel dependency chains) + depth-1 register prefetch (forces loads in
// flight; R4's VGPR=36 showed the compiler buffered almost nothing).
// newbuf = ctx copy only; pos-row overwrite happens in combine_kernel.
// ctx loads PLAIN (L3 retention across replays); newbuf stores NT.
// ---------------------------------------------------------------------------
__global__ __launch_bounds__(BDIM) void flash_kernel(const float* __restrict__ ctx,
                                                     const float* __restrict__ u,
                                                     float* __restrict__ newbuf,
                                                     float* __restrict__ pacc,
                                                     float* __restrict__ pml,
                                                     int nsplit) {
    const int b     = blockIdx.y;
    const int split = blockIdx.x;
    const int w     = threadIdx.x >> 6;
    const int lane  = threadIdx.x & 63;
    const int rpb   = S / nsplit;            // rows per block
    const int s0    = split * rpb;
    const int halfr = rpb >> 1;              // rows per stream

    const f4* ub = (const f4*)(u + (size_t)b * H);
    const f4 u0 = ub[lane], u1 = ub[64 + lane];

    const size_t baseA = (size_t)b * S + s0;          // stream A rows
    const size_t baseB = baseA + halfr;               // stream B rows

    float mA = -INFINITY, lA = 0.f; f4 aA0 = {0,0,0,0}, aA1 = {0,0,0,0};
    float mB = -INFINITY, lB = 0.f; f4 aB0 = {0,0,0,0}, aB1 = {0,0,0,0};

    int r = w;
    const f4* pA = (const f4*)(ctx + (baseA + r) * H);
    const f4* pB = (const f4*)(ctx + (baseB + r) * H);
    f4 cA0 = pA[lane], cA1 = pA[64 + lane];
    f4 cB0 = pB[lane], cB1 = pB[64 + lane];

    while (r < halfr) {
        const int rn = r + 4;
        const int rs = (rn < halfr) ? rn : r;          // clamp: re-load cur row
        const f4* nA = (const f4*)(ctx + (baseA + rs) * H);
        const f4* nB = (const f4*)(ctx + (baseB + rs) * H);
        const f4 nA0 = nA[lane], nA1 = nA[64 + lane];
        const f4 nB0 = nB[lane], nB1 = nB[64 + lane];

        f4* oA = (f4*)(newbuf + (baseA + r) * H);
        f4* oB = (f4*)(newbuf + (baseB + r) * H);
        __builtin_nontemporal_store(cA0, oA + lane);
        __builtin_nontemporal_store(cA1, oA + 64 + lane);
        __builtin_nontemporal_store(cB0, oB + lane);
        __builtin_nontemporal_store(cB1, oB + 64 + lane);

        float dA = dot8(cA0, cA1, u0, u1);
        float dB = dot8(cB0, cB1, u0, u1);
#pragma unroll
        for (int off = 32; off >= 1; off >>= 1) {      // interleaved chains
            dA += __shfl_xor(dA, off);
            dB += __shfl_xor(dB, off);
        }

        if (dA > mA + DEFER_THR) {                     // wave-uniform, rare
            const float sc = exp2f(mA - dA);
            aA0 *= sc; aA1 *= sc; lA *= sc; mA = dA;
        }
        if (dB > mB + DEFER_THR) {
            const float sc = exp2f(mB - dB);
            aB0 *= sc; aB1 *= sc; lB *= sc; mB = dB;
        }
        const float pAe = exp2f(dA - mA);
        const float pBe = exp2f(dB - mB);
        aA0 += pAe * cA0; aA1 += pAe * cA1; lA += pAe;
        aB0 += pBe * cB0; aB1 += pBe * cB1; lB += pBe;

        cA0 = nA0; cA1 = nA1; cB0 = nB0; cB1 = nB1;
        r = rn;
    }

    // ---- block-level reduce of 8 stream partials via LDS ----
    __shared__ float lacc[8][H];
    __shared__ float lml[8][2];
    f4* dA_ = (f4*)&lacc[w][0];
    f4* dB_ = (f4*)&lacc[4 + w][0];
    dA_[lane] = aA0; dA_[64 + lane] = aA1;
    dB_[lane] = aB0; dB_[64 + lane] = aB1;
    if (lane == 0) {
        lml[w][0] = mA;     lml[w][1] = lA;
        lml[4 + w][0] = mB; lml[4 + w][1] = lB;
    }
    __syncthreads();

    float M = -INFINITY;
#pragma unroll
    for (int j = 0; j < 8; ++j) M = fmaxf(M, lml[j][0]);
    float e[8];
#pragma unroll
    for (int j = 0; j < 8; ++j) e[j] = exp2f(lml[j][0] - M);

    const int t    = threadIdx.x;
    const int pidx = b * nsplit + split;
    float ca = 0.f, cb = 0.f;
#pragma unroll
    for (int j = 0; j < 8; ++j) {
        ca = fmaf(e[j], lacc[j][t], ca);
        cb = fmaf(e[j], lacc[j][256 + t], cb);
    }
    pacc[(size_t)pidx * H + t]       = ca;
    pacc[(size_t)pidx * H + 256 + t] = cb;
    if (t == 0) {
        float L = 0.f;
#pragma unroll
        for (int j = 0; j < 8; ++j) L = fmaf(e[j], lml[j][1], L);
        pml[2 * pidx] = M; pml[2 * pidx + 1] = L;
    }
}

// ---------------------------------------------------------------------------
// Kernel 3: combine per-block partials -> cntx[b,:]; also writes the cyclic-
// buffer row: newbuf[b,pos,:] = h_t[b,:] (ordered after flash).  grid=(B,2).
// ---------------------------------------------------------------------------
__global__ __launch_bounds__(BDIM) void combine_kernel(const float* __restrict__ pacc,
                                                       const float* __restrict__ pml,
                                                       const float* __restrict__ h_t,
                                                       const int* __restrict__ posp,
                                                       float* __restrict__ newbuf,
                                                       float* __restrict__ cntx,
                                                       int nsplit) {
    const int b    = blockIdx.x;
    const int half = blockIdx.y;
    const int t    = threadIdx.x;
    const int col  = half * 256 + t;

    int pos = posp[0] % S; if (pos < 0) pos += S;
    newbuf[((size_t)b * S + pos) * H + col] = h_t[b * H + col];

    __shared__ float lm[MAX_SPLIT], ll[MAX_SPLIT];
    for (int p = t; p < nsplit; p += BDIM) {
        lm[p] = pml[2 * (b * nsplit + p)];
        ll[p] = pml[2 * (b * nsplit + p) + 1];
    }
    __syncthreads();

    float M = -INFINITY;
    for (int p = 0; p < nsplit; ++p) M = fmaxf(M, lm[p]);

    float acc = 0.f, L = 0.f;
#pragma unroll 4
    for (int p = 0; p < nsplit; ++p) {
        const float e = exp2f(lm[p] - M);
        L   = fmaf(e, ll[p], L);
        acc = fmaf(e, pacc[(size_t)(b * nsplit + p) * H + col], acc);
    }
    cntx[b * H + col] = acc / L;
}

// ---------------------------------------------------------------------------
extern "C" void kernel_launch(void* const* d_in, const int* in_sizes, int n_in,
                              void* d_out, int out_size, void* d_ws, size_t ws_size,
                              hipStream_t stream) {
    const float* h_t = (const float*)d_in[0];
    const float* ctx = (const float*)d_in[1];
    const float* W   = (const float*)d_in[2];
    const int*   pos = (const int*)d_in[3];

    float* out    = (float*)d_out;
    float* cntx   = out;                     // [B,H]
    float* newbuf = out + (size_t)B * H;     // [B,S,H]

    // workspace layout: u [B*H] | pacc [B*nsplit*H] | pml [B*nsplit*2]
    char*  ws = (char*)d_ws;
    float* u  = (float*)ws;
    const size_t u_bytes = (size_t)B * H * sizeof(float);

    int nsplit = MAX_SPLIT;
    while (nsplit > 1) {
        const size_t need = u_bytes
                          + (size_t)B * nsplit * H * sizeof(float)
                          + (size_t)B * nsplit * 2 * sizeof(float);
        if (need <= ws_size) break;
        nsplit >>= 1;
    }
    float* pacc = (float*)(ws + u_bytes);
    float* pml  = pacc + (size_t)B * nsplit * H;

    u_kernel<<<dim3(H / BDIM, B), BDIM, 0, stream>>>(h_t, W, u);
    flash_kernel<<<dim3(nsplit, B), BDIM, 0, stream>>>(ctx, u, newbuf,
                                                       pacc, pml, nsplit);
    combine_kernel<<<dim3(B, 2), BDIM, 0, stream>>>(pacc, pml, h_t, pos,
                                                    newbuf, cntx, nsplit);
}